// Round 1
// baseline (10834.049 us; speedup 1.0000x reference)
//
#include <hip/hip_runtime.h>
#include <math.h>

#define PI_LEN 0.3141592653589793f   // pi / 10.0

__device__ __forceinline__ float fsilu(float x) {
  return x * __builtin_amdgcn_rcpf(1.f + __expf(-x));
}

__device__ __forceinline__ void atomic_add_f32(float* p, float v) {
  unsafeAtomicAdd(p, v);
}

#define LD8(dstv, p) { float4 _a = *(const float4*)(p); float4 _b = *(const float4*)((p)+4); \
  dstv[0]=_a.x; dstv[1]=_a.y; dstv[2]=_a.z; dstv[3]=_a.w; \
  dstv[4]=_b.x; dstv[5]=_b.y; dstv[6]=_b.z; dstv[7]=_b.w; }

// ---------------------------------------------------------------------------
// init: s_cur = s_in ; v_cur[n][c][f] = v_in[n][f][c]   (layout (N,3,32))
// ---------------------------------------------------------------------------
__global__ __launch_bounds__(256) void init_kernel(
    const float* __restrict__ s_in, const float* __restrict__ v_in,
    float* __restrict__ s_cur, float* __restrict__ v_cur, long total)
{
  long idx = (long)blockIdx.x * 256 + threadIdx.x;  // over N*32
  if (idx >= total) return;
  long n = idx >> 5; int g = (int)(idx & 31);
  s_cur[idx] = s_in[idx];
  #pragma unroll
  for (int c = 0; c < 3; ++c)
    v_cur[n*96 + c*32 + g] = v_in[n*96 + (long)g*3 + c];
}

// ---------------------------------------------------------------------------
// nodeA: Aout[n] = silu(s[n] @ w1 + b1) @ w2 + b2   (32 -> 32 -> 128)
// 8 nodes per 256-thread block, 32 lanes cooperate per node via LDS.
// ---------------------------------------------------------------------------
__global__ __launch_bounds__(256) void nodeA_kernel(
    const float* __restrict__ s, const float* __restrict__ w1,
    const float* __restrict__ b1, const float* __restrict__ w2,
    const float* __restrict__ b2, float* __restrict__ Aout, int N_)
{
  __shared__ float xld[8][32];
  __shared__ float hld[8][32];
  int tid = threadIdx.x, i = tid >> 5, g = tid & 31;
  long n = (long)blockIdx.x * 8 + i;
  bool ok = (n < N_);
  xld[i][g] = ok ? s[n*32 + g] : 0.f;
  __syncthreads();
  float acc = b1[g];
  for (int k = 0; k < 32; ++k) acc += xld[i][k] * w1[k*32 + g];
  hld[i][g] = fsilu(acc);
  __syncthreads();
  float o0 = b2[g], o1 = b2[32+g], o2 = b2[64+g], o3 = b2[96+g];
  for (int k = 0; k < 32; ++k) {
    float hk = hld[i][k];
    o0 += hk * w2[k*128 +      g];
    o1 += hk * w2[k*128 + 32 + g];
    o2 += hk * w2[k*128 + 64 + g];
    o3 += hk * w2[k*128 + 96 + g];
  }
  if (ok) {
    Aout[n*128 +      g] = o0;
    Aout[n*128 + 32 + g] = o1;
    Aout[n*128 + 64 + g] = o2;
    Aout[n*128 + 96 + g] = o3;
  }
}

// ---------------------------------------------------------------------------
// edge kernel: one thread per edge.
//   hB = silu(posenc(dist) @ w1B + b1B)
//   mix = Aout[src] * (hB @ w2B + b2B)        (gates|cpg|sed|sf, 4 x 32)
//   ds  = sf * s[src]            -> atomic into s_acc[dst]
//   dv  = sed*dir + gates*v[src] + cpg*cross(dir, v[dst]) -> atomic v_acc[dst]
// v layout is (N,3,32).
// ---------------------------------------------------------------------------
__global__ __launch_bounds__(256, 2) void edge_kernel(
    const int* __restrict__ ei, const float* __restrict__ dist,
    const float* __restrict__ edir, const float* __restrict__ s,
    const float* __restrict__ v, const float* __restrict__ Aout,
    const float* __restrict__ w1B, const float* __restrict__ b1B,
    const float* __restrict__ w2B, const float* __restrict__ b2B,
    float* __restrict__ s_acc, float* __restrict__ v_acc, int E_)
{
  int e = blockIdx.x * 256 + threadIdx.x;
  if (e >= E_) return;
  int src = ei[e];
  int dst = ei[E_ + e];
  float d  = dist[e];
  float dx = edir[3*e+0], dy = edir[3*e+1], dz = edir[3*e+2];

  // hB = silu(pe @ w1B + b1B);  pe[k] = sin(d*(k+1)*pi/L) k<16, cos(d*(k-15)*pi/L) else
  float hB[32];
  #pragma unroll
  for (int j = 0; j < 32; ++j) hB[j] = b1B[j];
  for (int k = 0; k < 16; ++k) {
    float pk = __sinf(d * (float)(k+1) * PI_LEN);
    #pragma unroll
    for (int j = 0; j < 32; ++j) hB[j] += pk * w1B[k*32 + j];
  }
  for (int k = 16; k < 32; ++k) {
    float pk = __cosf(d * (float)(k-15) * PI_LEN);
    #pragma unroll
    for (int j = 0; j < 32; ++j) hB[j] += pk * w1B[k*32 + j];
  }
  #pragma unroll
  for (int j = 0; j < 32; ++j) hB[j] = fsilu(hB[j]);

  const long abase = (long)src * 128;
  const long sbase = (long)src * 32;
  const long vsb   = (long)src * 96;
  const long vdb   = (long)dst * 96;
  const long sab   = (long)dst * 32;

  for (int t = 0; t < 4; ++t) {           // 4 tiles of 8 feature columns
    float acc0[8], acc1[8], acc2[8], acc3[8];
    #pragma unroll
    for (int j = 0; j < 8; ++j) {
      acc0[j] = b2B[      t*8 + j];
      acc1[j] = b2B[ 32 + t*8 + j];
      acc2[j] = b2B[ 64 + t*8 + j];
      acc3[j] = b2B[ 96 + t*8 + j];
    }
    #pragma unroll 32                      // must fully unroll: hB runtime index otherwise
    for (int k = 0; k < 32; ++k) {
      float hk = hB[k];
      const float* wr = w2B + k*128 + t*8;
      #pragma unroll
      for (int j = 0; j < 8; ++j) {
        acc0[j] += hk * wr[      j];
        acc1[j] += hk * wr[ 32 + j];
        acc2[j] += hk * wr[ 64 + j];
        acc3[j] += hk * wr[ 96 + j];
      }
    }
    float A0[8], A1[8], A2[8], A3[8], Sv[8];
    LD8(A0, Aout + abase +      t*8);
    LD8(A1, Aout + abase + 32 + t*8);
    LD8(A2, Aout + abase + 64 + t*8);
    LD8(A3, Aout + abase + 96 + t*8);
    LD8(Sv, s + sbase + t*8);
    float VS0[8], VS1[8], VS2[8], VD0[8], VD1[8], VD2[8];
    LD8(VS0, v + vsb +  0 + t*8);
    LD8(VS1, v + vsb + 32 + t*8);
    LD8(VS2, v + vsb + 64 + t*8);
    LD8(VD0, v + vdb +  0 + t*8);
    LD8(VD1, v + vdb + 32 + t*8);
    LD8(VD2, v + vdb + 64 + t*8);
    #pragma unroll
    for (int j = 0; j < 8; ++j) {
      float gates = acc0[j] * A0[j];
      float cpg   = acc1[j] * A1[j];
      float sed   = acc2[j] * A2[j];
      float sf    = acc3[j] * A3[j];
      atomic_add_f32(&s_acc[sab + t*8 + j], sf * Sv[j]);
      float vdx0 = VD0[j], vdy0 = VD1[j], vdz0 = VD2[j];
      float crx = dy*vdz0 - dz*vdy0;
      float cry = dz*vdx0 - dx*vdz0;
      float crz = dx*vdy0 - dy*vdx0;
      atomic_add_f32(&v_acc[vdb +  0 + t*8 + j], sed*dx + gates*VS0[j] + cpg*crx);
      atomic_add_f32(&v_acc[vdb + 32 + t*8 + j], sed*dy + gates*VS1[j] + cpg*cry);
      atomic_add_f32(&v_acc[vdb + 64 + t*8 + j], sed*dz + gates*VS2[j] + cpg*crz);
    }
  }
}

// ---------------------------------------------------------------------------
// node update: v += acc; s += acc; then PaiNN update block.
// 8 nodes / 256-thread block, 32 lanes per node.
// ---------------------------------------------------------------------------
__global__ __launch_bounds__(256) void node_update_kernel(
    const float* __restrict__ uU, const float* __restrict__ uV,
    const float* __restrict__ uw1, const float* __restrict__ ub1,
    const float* __restrict__ uw2, const float* __restrict__ ub2,
    float* __restrict__ s_cur, float* __restrict__ v_cur,
    const float* __restrict__ s_acc, const float* __restrict__ v_acc, int N_)
{
  __shared__ float vld[8][3][32];
  __shared__ float in64[8][64];
  __shared__ float hld[8][32];
  int tid = threadIdx.x, i = tid >> 5, g = tid & 31;
  long n = (long)blockIdx.x * 8 + i;
  bool ok = (n < N_);
  long vb = n * 96;
  float sval = 0.f;
  if (ok) {
    #pragma unroll
    for (int c = 0; c < 3; ++c)
      vld[i][c][g] = v_cur[vb + c*32 + g] + v_acc[vb + c*32 + g];
    sval = s_cur[n*32 + g] + s_acc[n*32 + g];
  } else {
    #pragma unroll
    for (int c = 0; c < 3; ++c) vld[i][c][g] = 0.f;
  }
  __syncthreads();
  float Vv0=0,Vv1=0,Vv2=0, Uv0=0,Uv1=0,Uv2=0;
  for (int f = 0; f < 32; ++f) {
    float wv = uV[f*32 + g];
    float wu = uU[f*32 + g];
    float v0 = vld[i][0][f], v1 = vld[i][1][f], v2 = vld[i][2][f];
    Vv0 += v0*wv; Vv1 += v1*wv; Vv2 += v2*wv;
    Uv0 += v0*wu; Uv1 += v1*wu; Uv2 += v2*wu;
  }
  float Vn = sqrtf(Vv0*Vv0 + Vv1*Vv1 + Vv2*Vv2);
  in64[i][g]      = Vn;
  in64[i][32 + g] = sval;
  __syncthreads();
  float h = ub1[g];
  for (int k = 0; k < 64; ++k) h += in64[i][k] * uw1[k*32 + g];
  h = fsilu(h);
  hld[i][g] = h;
  __syncthreads();
  float og = ub2[g], ossn = ub2[32+g], oadd = ub2[64+g];
  for (int k = 0; k < 32; ++k) {
    float hk = hld[i][k];
    og   += hk * uw2[k*96 +      g];
    ossn += hk * uw2[k*96 + 32 + g];
    oadd += hk * uw2[k*96 + 64 + g];
  }
  if (ok) {
    v_cur[vb +  0 + g] = vld[i][0][g] + og * Uv0;
    v_cur[vb + 32 + g] = vld[i][1][g] + og * Uv1;
    v_cur[vb + 64 + g] = vld[i][2][g] + og * Uv2;
    s_cur[n*32 + g] = sval + Vn*Vn*ossn + oadd;
  }
}

// ---------------------------------------------------------------------------
// readout: inv|gates = mlp(s); eqv = gates * (v @ ro_V)
// out layout: [N*32 inv][N*32*3 eqv, (n,f,c)]
// ---------------------------------------------------------------------------
__global__ __launch_bounds__(256) void readout_kernel(
    const float* __restrict__ s_cur, const float* __restrict__ v_cur,
    const float* __restrict__ w1, const float* __restrict__ b1,
    const float* __restrict__ w2, const float* __restrict__ b2,
    const float* __restrict__ roV, float* __restrict__ out, int N_)
{
  __shared__ float sld[8][32];
  __shared__ float hld[8][32];
  __shared__ float vld[8][3][32];
  int tid = threadIdx.x, i = tid >> 5, g = tid & 31;
  long n = (long)blockIdx.x * 8 + i;
  bool ok = (n < N_);
  sld[i][g] = ok ? s_cur[n*32 + g] : 0.f;
  #pragma unroll
  for (int c = 0; c < 3; ++c)
    vld[i][c][g] = ok ? v_cur[n*96 + c*32 + g] : 0.f;
  __syncthreads();
  float h = b1[g];
  for (int k = 0; k < 32; ++k) h += sld[i][k] * w1[k*32 + g];
  h = fsilu(h);
  hld[i][g] = h;
  __syncthreads();
  float inv = b2[g], gate = b2[32+g];
  for (int k = 0; k < 32; ++k) {
    float hk = hld[i][k];
    inv  += hk * w2[k*64 +      g];
    gate += hk * w2[k*64 + 32 + g];
  }
  float R0=0, R1=0, R2=0;
  for (int f = 0; f < 32; ++f) {
    float wv = roV[f*32 + g];
    R0 += vld[i][0][f]*wv; R1 += vld[i][1][f]*wv; R2 += vld[i][2][f]*wv;
  }
  if (ok) {
    out[n*32 + g] = inv;
    long eb = (long)N_*32 + n*96 + (long)g*3;
    out[eb+0] = gate*R0; out[eb+1] = gate*R1; out[eb+2] = gate*R2;
  }
}

// ---------------------------------------------------------------------------
extern "C" void kernel_launch(void* const* d_in, const int* in_sizes, int n_in,
                              void* d_out, int out_size, void* d_ws, size_t ws_size,
                              hipStream_t stream)
{
  const float* s_in  = (const float*)d_in[0];
  const float* v_in  = (const float*)d_in[1];
  const int*   ei    = (const int*)  d_in[2];
  const float* dist  = (const float*)d_in[3];
  const float* edir  = (const float*)d_in[4];
  const float* mp_w1 = (const float*)d_in[5];
  const float* mp_b1 = (const float*)d_in[6];
  const float* mp_w2 = (const float*)d_in[7];
  const float* mp_b2 = (const float*)d_in[8];
  const float* mw_w1 = (const float*)d_in[9];
  const float* mw_b1 = (const float*)d_in[10];
  const float* mw_w2 = (const float*)d_in[11];
  const float* mw_b2 = (const float*)d_in[12];
  const float* u_U   = (const float*)d_in[13];
  const float* u_V   = (const float*)d_in[14];
  const float* u_w1  = (const float*)d_in[15];
  const float* u_b1  = (const float*)d_in[16];
  const float* u_w2  = (const float*)d_in[17];
  const float* u_b2  = (const float*)d_in[18];
  const float* ro_w1 = (const float*)d_in[19];
  const float* ro_b1 = (const float*)d_in[20];
  const float* ro_w2 = (const float*)d_in[21];
  const float* ro_b2 = (const float*)d_in[22];
  const float* ro_V  = (const float*)d_in[23];

  int N_ = in_sizes[0] / 32;
  int E_ = in_sizes[3];

  float* s_cur = (float*)d_ws;                    // N*32
  float* v_cur = s_cur + (size_t)N_*32;           // N*96
  float* s_acc = v_cur + (size_t)N_*96;           // N*32
  float* v_acc = s_acc + (size_t)N_*32;           // N*96
  float* Aout  = v_acc + (size_t)N_*96;           // N*128

  int nodeBlocks = (N_ + 7) / 8;
  long total     = (long)N_ * 32;
  int initBlocks = (int)((total + 255) / 256);
  int edgeBlocks = (E_ + 255) / 256;

  init_kernel<<<initBlocks, 256, 0, stream>>>(s_in, v_in, s_cur, v_cur, total);

  for (int l = 0; l < 2; ++l) {
    hipMemsetAsync(s_acc, 0, (size_t)N_*32*sizeof(float), stream);
    hipMemsetAsync(v_acc, 0, (size_t)N_*96*sizeof(float), stream);
    nodeA_kernel<<<nodeBlocks, 256, 0, stream>>>(
        s_cur, mp_w1 + l*1024, mp_b1 + l*32, mp_w2 + l*4096, mp_b2 + l*128, Aout, N_);
    edge_kernel<<<edgeBlocks, 256, 0, stream>>>(
        ei, dist, edir, s_cur, v_cur, Aout,
        mw_w1 + l*1024, mw_b1 + l*32, mw_w2 + l*4096, mw_b2 + l*128,
        s_acc, v_acc, E_);
    node_update_kernel<<<nodeBlocks, 256, 0, stream>>>(
        u_U + l*1024, u_V + l*1024, u_w1 + l*2048, u_b1 + l*32,
        u_w2 + l*3072, u_b2 + l*96, s_cur, v_cur, s_acc, v_acc, N_);
  }

  readout_kernel<<<nodeBlocks, 256, 0, stream>>>(
      s_cur, v_cur, ro_w1, ro_b1, ro_w2, ro_b2, ro_V, (float*)d_out, N_);
}

// Round 2
// 2205.239 us; speedup vs baseline: 4.9129x; 4.9129x over previous
//
#include <hip/hip_runtime.h>
#include <math.h>

#define PI_LEN 0.3141592653589793f   // pi / 10.0

__device__ __forceinline__ float fsilu(float x) {
  return x * __builtin_amdgcn_rcpf(1.f + __expf(-x));
}

// ---------------------------------------------------------------------------
// CSR build: hist -> scan -> scatter (edge_index constant across layers)
// ---------------------------------------------------------------------------
__global__ __launch_bounds__(256) void hist_kernel(const int* __restrict__ ei,
                                                   int* __restrict__ deg, int E_) {
  int e = blockIdx.x * 256 + threadIdx.x;
  if (e < E_) atomicAdd(&deg[ei[E_ + e]], 1);
}

__global__ __launch_bounds__(1024) void scan_kernel(const int* __restrict__ deg,
                                                    int* __restrict__ off,
                                                    int* __restrict__ cursor, int N_) {
  __shared__ int wtot[16];
  __shared__ int carry_s;
  int tid = threadIdx.x, lane = tid & 63, wid = tid >> 6;
  if (tid == 0) carry_s = 0;
  __syncthreads();
  int nch = (N_ + 8191) / 8192;
  for (int c = 0; c < nch; ++c) {
    int base_idx = c * 8192 + tid * 8;
    int x[8]; int mysum = 0;
    #pragma unroll
    for (int j = 0; j < 8; ++j) { int idx = base_idx + j; x[j] = (idx < N_) ? deg[idx] : 0; mysum += x[j]; }
    int incl = mysum;
    #pragma unroll
    for (int s = 1; s < 64; s <<= 1) { int t = __shfl_up(incl, s, 64); if (lane >= s) incl += t; }
    if (lane == 63) wtot[wid] = incl;
    __syncthreads();
    if (wid == 0) {
      int wt = (lane < 16) ? wtot[lane] : 0;
      #pragma unroll
      for (int s = 1; s < 16; s <<= 1) { int t = __shfl_up(wt, s, 64); if (lane >= s) wt += t; }
      if (lane < 16) wtot[lane] = wt;
    }
    __syncthreads();
    int wexcl = (wid > 0) ? wtot[wid - 1] : 0;
    int run = carry_s + wexcl + (incl - mysum);
    #pragma unroll
    for (int j = 0; j < 8; ++j) {
      int idx = base_idx + j;
      if (idx < N_) { off[idx] = run; cursor[idx] = run; }
      run += x[j];
    }
    __syncthreads();
    if (tid == 0) carry_s += wtot[15];
    __syncthreads();
  }
  if (tid == 0) off[N_] = carry_s;
}

__global__ __launch_bounds__(256) void scatter_kernel(
    const int* __restrict__ ei, const float* __restrict__ dist,
    const float* __restrict__ edir, int* __restrict__ cursor,
    int* __restrict__ srcp, float4* __restrict__ edata, int E_) {
  int e = blockIdx.x * 256 + threadIdx.x;
  if (e < E_) {
    int dst = ei[E_ + e];
    int pos = atomicAdd(&cursor[dst], 1);
    srcp[pos] = ei[e];
    edata[pos] = make_float4(edir[3*e], edir[3*e+1], edir[3*e+2], dist[e]);
  }
}

// ---------------------------------------------------------------------------
// nodeA: Aout[n] = silu(s[n] @ w1 + b1) @ w2 + b2  -> packed float4 per (n,g)
// Aout4[n*32+g] = (gates_col, cpg_col, sed_col, sf_col) at feature g
// ---------------------------------------------------------------------------
__global__ __launch_bounds__(256) void nodeA_kernel(
    const float* __restrict__ s, const float* __restrict__ w1,
    const float* __restrict__ b1, const float* __restrict__ w2,
    const float* __restrict__ b2, float4* __restrict__ Aout4, int N_)
{
  __shared__ float xld[8][32];
  __shared__ float hld[8][32];
  int tid = threadIdx.x, i = tid >> 5, g = tid & 31;
  long n = (long)blockIdx.x * 8 + i;
  bool ok = (n < N_);
  xld[i][g] = ok ? s[n*32 + g] : 0.f;
  __syncthreads();
  float acc = b1[g];
  for (int k = 0; k < 32; ++k) acc += xld[i][k] * w1[k*32 + g];
  hld[i][g] = fsilu(acc);
  __syncthreads();
  float o0 = b2[g], o1 = b2[32+g], o2 = b2[64+g], o3 = b2[96+g];
  for (int k = 0; k < 32; ++k) {
    float hk = hld[i][k];
    o0 += hk * w2[k*128 +      g];
    o1 += hk * w2[k*128 + 32 + g];
    o2 += hk * w2[k*128 + 64 + g];
    o3 += hk * w2[k*128 + 96 + g];
  }
  if (ok) Aout4[n*32 + g] = make_float4(o0, o1, o2, o3);
}

// ---------------------------------------------------------------------------
// gather + fused node update. 8 nodes/block, 32 lanes/node.
// Per edge (batched x4): filter-MLP inline (Chebyshev posenc recurrence,
// shfl-broadcast of h, w2 in LDS transposed for ds_read_b128), gather src
// state, accumulate dv/ds in registers. Then fused PaiNN update block.
// v layout: (N, F, 3)  (matches input layout).
// ---------------------------------------------------------------------------
__global__ __launch_bounds__(256) void gather_update_kernel(
    const int* __restrict__ off, const int* __restrict__ srcp,
    const float4* __restrict__ edata,
    const float* __restrict__ s_prev, const float* __restrict__ v_prev,
    const float4* __restrict__ Aout4,
    const float* __restrict__ w1B, const float* __restrict__ b1B,
    const float* __restrict__ w2B, const float* __restrict__ b2B,
    const float* __restrict__ uU, const float* __restrict__ uV,
    const float* __restrict__ uw1, const float* __restrict__ ub1,
    const float* __restrict__ uw2, const float* __restrict__ ub2,
    float* __restrict__ s_out, float* __restrict__ v_out, int N_)
{
  // phase1 layout: w1[0..1023], w2t[1024..5119], b1[5120..5151], b2[5152..5279]
  // phase2 layout: uU[0..1023], uV[1024..2047], uw1[2048..4095], uw2[4096..7167],
  //                ub1[7168..7199], ub2[7200..7295], vld[7296..8063],
  //                in64[8064..8575], hld[8576..8831]
  __shared__ float smem[8832];
  int tid = threadIdx.x, i = tid >> 5, g = tid & 31;

  for (int t = tid; t < 1024; t += 256) smem[t] = w1B[t];
  for (int t = tid; t < 4096; t += 256) {
    int k = t >> 7, q = (t >> 5) & 3, gg = t & 31;
    smem[1024 + (k*32 + gg)*4 + q] = w2B[t];       // transposed pack for b128
  }
  if (tid < 32)  smem[5120 + tid] = b1B[tid];
  if (tid < 128) smem[5152 + tid] = b2B[tid];
  __syncthreads();

  int n = blockIdx.x * 8 + i;
  bool ok = (n < N_);
  float vd0 = 0, vd1 = 0, vd2 = 0, s_own = 0;
  int pstart = 0, pend = 0;
  if (ok) {
    const float* vp = v_prev + (long)n*96 + g*3;
    vd0 = vp[0]; vd1 = vp[1]; vd2 = vp[2];
    s_own = s_prev[(long)n*32 + g];
    pstart = off[n]; pend = off[n + 1];
  }
  float acc_s = 0, av0 = 0, av1 = 0, av2 = 0;

  for (int p0 = pstart; p0 < pend; p0 += 4) {
    int nb = pend - p0; if (nb > 4) nb = 4;
    int srcs[4]; float4 ed[4];
    #pragma unroll
    for (int b = 0; b < 4; ++b) {
      int p = (b < nb) ? p0 + b : p0;
      srcs[b] = srcp[p]; ed[b] = edata[p];
    }
    // layer1: hb = b1 + sum_r sin((r+1)th)*w1[r] + cos((r+1)th)*w1[16+r]
    float hb[4], sr[4], cr[4], s1[4], c1[4];
    #pragma unroll
    for (int b = 0; b < 4; ++b) {
      float th = ed[b].w * PI_LEN;
      s1[b] = __sinf(th); c1[b] = __cosf(th);
      sr[b] = s1[b]; cr[b] = c1[b];
      hb[b] = smem[5120 + g];
    }
    #pragma unroll
    for (int r = 0; r < 16; ++r) {
      float w_s = smem[r*32 + g];
      float w_c = smem[(16 + r)*32 + g];
      #pragma unroll
      for (int b = 0; b < 4; ++b) {
        hb[b] += sr[b]*w_s + cr[b]*w_c;
        float ns_ = sr[b]*c1[b] + cr[b]*s1[b];
        float nc_ = cr[b]*c1[b] - sr[b]*s1[b];
        sr[b] = ns_; cr[b] = nc_;
      }
    }
    #pragma unroll
    for (int b = 0; b < 4; ++b) hb[b] = fsilu(hb[b]);
    // layer2: m[b][q] = b2[q*32+g] + sum_k hb[k]*w2[k][q*32+g]
    float m[4][4];
    #pragma unroll
    for (int b = 0; b < 4; ++b) {
      m[b][0] = smem[5152 + g];      m[b][1] = smem[5152 + 32 + g];
      m[b][2] = smem[5152 + 64 + g]; m[b][3] = smem[5152 + 96 + g];
    }
    #pragma unroll
    for (int k = 0; k < 32; ++k) {
      float4 w = *(const float4*)&smem[1024 + (k*32 + g)*4];
      #pragma unroll
      for (int b = 0; b < 4; ++b) {
        float hk = __shfl(hb[b], k, 32);
        m[b][0] += hk*w.x; m[b][1] += hk*w.y; m[b][2] += hk*w.z; m[b][3] += hk*w.w;
      }
    }
    // gather src state + accumulate
    #pragma unroll
    for (int b = 0; b < 4; ++b) {
      if (b >= nb) break;
      long sb_ = (long)srcs[b];
      float4 A = Aout4[sb_*32 + g];
      float sv = s_prev[sb_*32 + g];
      const float* vp = v_prev + sb_*96 + g*3;
      float vs0 = vp[0], vs1 = vp[1], vs2 = vp[2];
      float gates = m[b][0]*A.x, cpg = m[b][1]*A.y, sed = m[b][2]*A.z, sf = m[b][3]*A.w;
      acc_s += sf * sv;
      float dx = ed[b].x, dy = ed[b].y, dz = ed[b].z;
      float crx = dy*vd2 - dz*vd1;
      float cry = dz*vd0 - dx*vd2;
      float crz = dx*vd1 - dy*vd0;
      av0 += sed*dx + gates*vs0 + cpg*crx;
      av1 += sed*dy + gates*vs1 + cpg*cry;
      av2 += sed*dz + gates*vs2 + cpg*crz;
    }
  }

  // ---- fused node update ----
  __syncthreads();   // everyone done with phase-1 smem
  for (int t = tid; t < 1024; t += 256) { smem[t] = uU[t]; smem[1024 + t] = uV[t]; }
  for (int t = tid; t < 2048; t += 256) smem[2048 + t] = uw1[t];
  for (int t = tid; t < 3072; t += 256) smem[4096 + t] = uw2[t];
  if (tid < 32) smem[7168 + tid] = ub1[tid];
  if (tid < 96) smem[7200 + tid] = ub2[tid];
  float nv0 = vd0 + av0, nv1 = vd1 + av1, nv2 = vd2 + av2;
  float ns  = s_own + acc_s;
  smem[7296 + i*96 + g*3 + 0] = nv0;
  smem[7296 + i*96 + g*3 + 1] = nv1;
  smem[7296 + i*96 + g*3 + 2] = nv2;
  __syncthreads();
  float Vv0=0,Vv1=0,Vv2=0,Uv0=0,Uv1=0,Uv2=0;
  for (int f = 0; f < 32; ++f) {
    float wu = smem[f*32 + g];
    float wv = smem[1024 + f*32 + g];
    float v0 = smem[7296 + i*96 + f*3 + 0];
    float v1 = smem[7296 + i*96 + f*3 + 1];
    float v2 = smem[7296 + i*96 + f*3 + 2];
    Vv0 += v0*wv; Vv1 += v1*wv; Vv2 += v2*wv;
    Uv0 += v0*wu; Uv1 += v1*wu; Uv2 += v2*wu;
  }
  float Vn = sqrtf(Vv0*Vv0 + Vv1*Vv1 + Vv2*Vv2);
  smem[8064 + i*64 + g]      = Vn;
  smem[8064 + i*64 + 32 + g] = ns;
  __syncthreads();
  float h = smem[7168 + g];
  for (int k = 0; k < 64; ++k) h += smem[8064 + i*64 + k] * smem[2048 + k*32 + g];
  h = fsilu(h);
  smem[8576 + i*32 + g] = h;
  __syncthreads();
  float og = smem[7200 + g], ossn = smem[7200 + 32 + g], oadd = smem[7200 + 64 + g];
  for (int k = 0; k < 32; ++k) {
    float hk = smem[8576 + i*32 + k];
    og   += hk * smem[4096 + k*96 +      g];
    ossn += hk * smem[4096 + k*96 + 32 + g];
    oadd += hk * smem[4096 + k*96 + 64 + g];
  }
  if (ok) {
    float* vo = v_out + (long)n*96 + g*3;
    vo[0] = nv0 + og*Uv0;
    vo[1] = nv1 + og*Uv1;
    vo[2] = nv2 + og*Uv2;
    s_out[(long)n*32 + g] = ns + Vn*Vn*ossn + oadd;
  }
}

// ---------------------------------------------------------------------------
// readout: inv|gates = mlp(s); eqv = gates * (v @ ro_V)
// ---------------------------------------------------------------------------
__global__ __launch_bounds__(256) void readout_kernel(
    const float* __restrict__ s_cur, const float* __restrict__ v_cur,
    const float* __restrict__ w1, const float* __restrict__ b1,
    const float* __restrict__ w2, const float* __restrict__ b2,
    const float* __restrict__ roV, float* __restrict__ out, int N_)
{
  __shared__ float sld[8][32];
  __shared__ float hld[8][32];
  __shared__ float vld[8][96];
  int tid = threadIdx.x, i = tid >> 5, g = tid & 31;
  long n = (long)blockIdx.x * 8 + i;
  bool ok = (n < N_);
  if (ok) {
    sld[i][g] = s_cur[n*32 + g];
    const float* vp = v_cur + n*96 + g*3;
    vld[i][g*3+0] = vp[0]; vld[i][g*3+1] = vp[1]; vld[i][g*3+2] = vp[2];
  } else {
    sld[i][g] = 0.f;
    vld[i][g*3+0] = vld[i][g*3+1] = vld[i][g*3+2] = 0.f;
  }
  __syncthreads();
  float h = b1[g];
  for (int k = 0; k < 32; ++k) h += sld[i][k] * w1[k*32 + g];
  h = fsilu(h);
  hld[i][g] = h;
  __syncthreads();
  float inv = b2[g], gate = b2[32+g];
  for (int k = 0; k < 32; ++k) {
    float hk = hld[i][k];
    inv  += hk * w2[k*64 +      g];
    gate += hk * w2[k*64 + 32 + g];
  }
  float R0=0, R1=0, R2=0;
  for (int f = 0; f < 32; ++f) {
    float wv = roV[f*32 + g];
    R0 += vld[i][f*3+0]*wv; R1 += vld[i][f*3+1]*wv; R2 += vld[i][f*3+2]*wv;
  }
  if (ok) {
    out[n*32 + g] = inv;
    long eb = (long)N_*32 + n*96 + (long)g*3;
    out[eb+0] = gate*R0; out[eb+1] = gate*R1; out[eb+2] = gate*R2;
  }
}

// ---------------------------------------------------------------------------
extern "C" void kernel_launch(void* const* d_in, const int* in_sizes, int n_in,
                              void* d_out, int out_size, void* d_ws, size_t ws_size,
                              hipStream_t stream)
{
  const float* s_in  = (const float*)d_in[0];
  const float* v_in  = (const float*)d_in[1];   // (N, F, 3)
  const int*   ei    = (const int*)  d_in[2];
  const float* dist  = (const float*)d_in[3];
  const float* edir  = (const float*)d_in[4];
  const float* mp_w1 = (const float*)d_in[5];
  const float* mp_b1 = (const float*)d_in[6];
  const float* mp_w2 = (const float*)d_in[7];
  const float* mp_b2 = (const float*)d_in[8];
  const float* mw_w1 = (const float*)d_in[9];
  const float* mw_b1 = (const float*)d_in[10];
  const float* mw_w2 = (const float*)d_in[11];
  const float* mw_b2 = (const float*)d_in[12];
  const float* u_U   = (const float*)d_in[13];
  const float* u_V   = (const float*)d_in[14];
  const float* u_w1  = (const float*)d_in[15];
  const float* u_b1  = (const float*)d_in[16];
  const float* u_w2  = (const float*)d_in[17];
  const float* u_b2  = (const float*)d_in[18];
  const float* ro_w1 = (const float*)d_in[19];
  const float* ro_b1 = (const float*)d_in[20];
  const float* ro_w2 = (const float*)d_in[21];
  const float* ro_b2 = (const float*)d_in[22];
  const float* ro_V  = (const float*)d_in[23];

  int N_ = in_sizes[0] / 32;
  int E_ = in_sizes[3];

  float*  sA    = (float*)d_ws;                       // N*32
  float*  vA    = sA + (size_t)N_*32;                 // N*96
  float*  sB    = vA + (size_t)N_*96;                 // N*32
  float*  vB    = sB + (size_t)N_*32;                 // N*96
  float4* Aout4 = (float4*)(vB + (size_t)N_*96);      // N*32 float4
  float4* edata = Aout4 + (size_t)N_*32;              // E float4
  int*    srcp  = (int*)(edata + (size_t)E_);         // E
  int*    deg   = srcp + E_;                          // N
  int*    off   = deg + N_;                           // N+1
  int*    cursor= off + N_ + 1;                       // N

  int nodeBlocks = (N_ + 7) / 8;
  int edgeBlocks = (E_ + 255) / 256;

  // --- CSR build (once; edge_index constant across layers) ---
  hipMemsetAsync(deg, 0, (size_t)N_ * sizeof(int), stream);
  hist_kernel<<<edgeBlocks, 256, 0, stream>>>(ei, deg, E_);
  scan_kernel<<<1, 1024, 0, stream>>>(deg, off, cursor, N_);
  scatter_kernel<<<edgeBlocks, 256, 0, stream>>>(ei, dist, edir, cursor, srcp, edata, E_);

  const float* s_cur = s_in;  const float* v_cur = v_in;
  float* s_nxt = sB;  float* v_nxt = vB;
  for (int l = 0; l < 2; ++l) {
    nodeA_kernel<<<nodeBlocks, 256, 0, stream>>>(
        s_cur, mp_w1 + l*1024, mp_b1 + l*32, mp_w2 + l*4096, mp_b2 + l*128, Aout4, N_);
    gather_update_kernel<<<nodeBlocks, 256, 0, stream>>>(
        off, srcp, edata, s_cur, v_cur, Aout4,
        mw_w1 + l*1024, mw_b1 + l*32, mw_w2 + l*4096, mw_b2 + l*128,
        u_U + l*1024, u_V + l*1024, u_w1 + l*2048, u_b1 + l*32,
        u_w2 + l*3072, u_b2 + l*96,
        s_nxt, v_nxt, N_);
    s_cur = s_nxt; v_cur = v_nxt;
    s_nxt = sA;    v_nxt = vA;     // layer1 writes the A buffers
  }

  readout_kernel<<<nodeBlocks, 256, 0, stream>>>(
      s_cur, v_cur, ro_w1, ro_b1, ro_w2, ro_b2, ro_V, (float*)d_out, N_);
}

// Round 3
// 782.929 us; speedup vs baseline: 13.8379x; 2.8167x over previous
//
#include <hip/hip_runtime.h>
#include <math.h>

#define PI_LEN 0.3141592653589793f   // pi / 10.0
#define LEN_F  10.0f
#define TBL    4096                   // table rows = TBL+1

__device__ __forceinline__ float fsilu(float x) {
  return x * __builtin_amdgcn_rcpf(1.f + __expf(-x));
}

// ---------------------------------------------------------------------------
// CSR build: hist -> scan -> scatter (edge_index constant across layers)
// ---------------------------------------------------------------------------
__global__ __launch_bounds__(256) void hist_kernel(const int* __restrict__ ei,
                                                   int* __restrict__ deg, int E_) {
  int e = blockIdx.x * 256 + threadIdx.x;
  if (e < E_) atomicAdd(&deg[ei[E_ + e]], 1);
}

__global__ __launch_bounds__(1024) void scan_kernel(const int* __restrict__ deg,
                                                    int* __restrict__ off,
                                                    int* __restrict__ cursor, int N_) {
  __shared__ int wtot[16];
  __shared__ int carry_s;
  int tid = threadIdx.x, lane = tid & 63, wid = tid >> 6;
  if (tid == 0) carry_s = 0;
  __syncthreads();
  int nch = (N_ + 8191) / 8192;
  for (int c = 0; c < nch; ++c) {
    int base_idx = c * 8192 + tid * 8;
    int x[8]; int mysum = 0;
    #pragma unroll
    for (int j = 0; j < 8; ++j) { int idx = base_idx + j; x[j] = (idx < N_) ? deg[idx] : 0; mysum += x[j]; }
    int incl = mysum;
    #pragma unroll
    for (int s = 1; s < 64; s <<= 1) { int t = __shfl_up(incl, s, 64); if (lane >= s) incl += t; }
    if (lane == 63) wtot[wid] = incl;
    __syncthreads();
    if (wid == 0) {
      int wt = (lane < 16) ? wtot[lane] : 0;
      #pragma unroll
      for (int s = 1; s < 16; s <<= 1) { int t = __shfl_up(wt, s, 64); if (lane >= s) wt += t; }
      if (lane < 16) wtot[lane] = wt;
    }
    __syncthreads();
    int wexcl = (wid > 0) ? wtot[wid - 1] : 0;
    int run = carry_s + wexcl + (incl - mysum);
    #pragma unroll
    for (int j = 0; j < 8; ++j) {
      int idx = base_idx + j;
      if (idx < N_) { off[idx] = run; cursor[idx] = run; }
      run += x[j];
    }
    __syncthreads();
    if (tid == 0) carry_s += wtot[15];
    __syncthreads();
  }
  if (tid == 0) off[N_] = carry_s;
}

__global__ __launch_bounds__(256) void scatter_kernel(
    const int* __restrict__ ei, const float* __restrict__ dist,
    const float* __restrict__ edir, int* __restrict__ cursor,
    int* __restrict__ srcp, float4* __restrict__ edata, int E_) {
  int e = blockIdx.x * 256 + threadIdx.x;
  if (e < E_) {
    int dst = ei[E_ + e];
    int pos = atomicAdd(&cursor[dst], 1);
    srcp[pos] = ei[e];
    edata[pos] = make_float4(edir[3*e], edir[3*e+1], edir[3*e+2], dist[e]);
  }
}

// ---------------------------------------------------------------------------
// nodeA: A[n] = silu(s[n] @ w1 + b1) @ w2 + b2 ; Aout4[n*32+g] =
//   (gates_col, cpg_col, sed_col, sf_col * s[n][g])   <- s folded into .w
// ---------------------------------------------------------------------------
__global__ __launch_bounds__(256) void nodeA_kernel(
    const float* __restrict__ s, const float* __restrict__ w1,
    const float* __restrict__ b1, const float* __restrict__ w2,
    const float* __restrict__ b2, float4* __restrict__ Aout4, int N_)
{
  __shared__ float xld[8][32];
  __shared__ float hld[8][32];
  int tid = threadIdx.x, i = tid >> 5, g = tid & 31;
  long n = (long)blockIdx.x * 8 + i;
  bool ok = (n < N_);
  xld[i][g] = ok ? s[n*32 + g] : 0.f;
  __syncthreads();
  float acc = b1[g];
  for (int k = 0; k < 32; ++k) acc += xld[i][k] * w1[k*32 + g];
  hld[i][g] = fsilu(acc);
  __syncthreads();
  float o0 = b2[g], o1 = b2[32+g], o2 = b2[64+g], o3 = b2[96+g];
  for (int k = 0; k < 32; ++k) {
    float hk = hld[i][k];
    o0 += hk * w2[k*128 +      g];
    o1 += hk * w2[k*128 + 32 + g];
    o2 += hk * w2[k*128 + 64 + g];
    o3 += hk * w2[k*128 + 96 + g];
  }
  if (ok) Aout4[n*32 + g] = make_float4(o0, o1, o2, o3 * xld[i][g]);
}

// ---------------------------------------------------------------------------
// filter table: tbl4[t*32+g] = mlpB(posenc(t*LEN/TBL)) packed (q0..q3) at g
// ---------------------------------------------------------------------------
__global__ __launch_bounds__(256) void tbl_kernel(
    const float* __restrict__ w1, const float* __restrict__ b1,
    const float* __restrict__ w2, const float* __restrict__ b2,
    float4* __restrict__ tbl4)
{
  __shared__ float peld[8][32];
  __shared__ float hld[8][32];
  int tid = threadIdx.x, i = tid >> 5, g = tid & 31;
  int t = blockIdx.x * 8 + i;
  bool okt = (t <= TBL);
  float d = (float)t * (LEN_F / (float)TBL);
  float pe = (g < 16) ? __sinf(d * (float)(g + 1) * PI_LEN)
                      : __cosf(d * (float)(g - 15) * PI_LEN);
  peld[i][g] = pe;
  __syncthreads();
  float h = b1[g];
  for (int k = 0; k < 32; ++k) h += peld[i][k] * w1[k*32 + g];
  hld[i][g] = fsilu(h);
  __syncthreads();
  float o0 = b2[g], o1 = b2[32+g], o2 = b2[64+g], o3 = b2[96+g];
  for (int k = 0; k < 32; ++k) {
    float hk = hld[i][k];
    o0 += hk * w2[k*128 +      g];
    o1 += hk * w2[k*128 + 32 + g];
    o2 += hk * w2[k*128 + 64 + g];
    o3 += hk * w2[k*128 + 96 + g];
  }
  if (okt) tbl4[(long)t*32 + g] = make_float4(o0, o1, o2, o3);
}

// ---------------------------------------------------------------------------
// gather + fused node update. 4 nodes/block, one wave64 per node:
// lane = (hf, g); the two 32-lane halves each take every other edge.
// Per edge: table lerp (L2-hot) + A/v gather + ~40 VALU. No LDS in the loop.
// ---------------------------------------------------------------------------
__global__ __launch_bounds__(256) void gather_update_kernel(
    const int* __restrict__ off, const int* __restrict__ srcp,
    const float4* __restrict__ edata, const float4* __restrict__ tbl4,
    const float* __restrict__ s_prev, const float* __restrict__ v_prev,
    const float4* __restrict__ Aout4,
    const float* __restrict__ uU, const float* __restrict__ uV,
    const float* __restrict__ uw1, const float* __restrict__ ub1,
    const float* __restrict__ uw2, const float* __restrict__ ub2,
    float* __restrict__ s_out, float* __restrict__ v_out, int N_)
{
  __shared__ float vld[4][96];
  __shared__ float in64[4][64];
  __shared__ float hld[4][32];
  int tid = threadIdx.x, w = tid >> 6, lane = tid & 63, g = lane & 31, hf = lane >> 5;
  int n = blockIdx.x * 4 + w;
  bool ok = (n < N_);
  float vd0 = 0, vd1 = 0, vd2 = 0, s_own = 0;
  int pstart = 0, pend = 0;
  if (ok) {
    const float* vp = v_prev + (long)n*96 + g*3;
    vd0 = vp[0]; vd1 = vp[1]; vd2 = vp[2];
    s_own = s_prev[(long)n*32 + g];
    pstart = off[n]; pend = off[n + 1];
  }
  float acc_s = 0, av0 = 0, av1 = 0, av2 = 0;
  const float inv_step = (float)TBL / LEN_F;

  int p = pstart + hf;
  // two edges per half-wave in flight
  for (; p + 2 < pend; p += 4) {
    int  sA_ = srcp[p], sB_ = srcp[p + 2];
    float4 eA = edata[p], eB = edata[p + 2];
    float4 Aa = Aout4[(long)sA_*32 + g];
    float4 Ab = Aout4[(long)sB_*32 + g];
    const float* vpa = v_prev + (long)sA_*96 + g*3;
    const float* vpb = v_prev + (long)sB_*96 + g*3;
    float va0 = vpa[0], va1 = vpa[1], va2 = vpa[2];
    float vb0 = vpb[0], vb1 = vpb[1], vb2 = vpb[2];
    float xa = eA.w * inv_step, xb = eB.w * inv_step;
    float fa = floorf(xa), fb = floorf(xb);
    int ia = (int)fa; if (ia > TBL-1) ia = TBL-1;
    int ib = (int)fb; if (ib > TBL-1) ib = TBL-1;
    float fra = xa - fa, frb = xb - fb;
    float4 m0a = tbl4[(long)ia*32 + g],  m1a = tbl4[(long)(ia+1)*32 + g];
    float4 m0b = tbl4[(long)ib*32 + g],  m1b = tbl4[(long)(ib+1)*32 + g];
    float ga = m0a.x + fra*(m1a.x - m0a.x);
    float ca = m0a.y + fra*(m1a.y - m0a.y);
    float da = m0a.z + fra*(m1a.z - m0a.z);
    float sa = m0a.w + fra*(m1a.w - m0a.w);
    float gb = m0b.x + frb*(m1b.x - m0b.x);
    float cb = m0b.y + frb*(m1b.y - m0b.y);
    float db = m0b.z + frb*(m1b.z - m0b.z);
    float sb2 = m0b.w + frb*(m1b.w - m0b.w);
    float gates = ga*Aa.x, cpg = ca*Aa.y, sed = da*Aa.z;
    acc_s += sa*Aa.w;
    float crx = eA.y*vd2 - eA.z*vd1;
    float cry = eA.z*vd0 - eA.x*vd2;
    float crz = eA.x*vd1 - eA.y*vd0;
    av0 += sed*eA.x + gates*va0 + cpg*crx;
    av1 += sed*eA.y + gates*va1 + cpg*cry;
    av2 += sed*eA.z + gates*va2 + cpg*crz;
    gates = gb*Ab.x; cpg = cb*Ab.y; sed = db*Ab.z;
    acc_s += sb2*Ab.w;
    crx = eB.y*vd2 - eB.z*vd1;
    cry = eB.z*vd0 - eB.x*vd2;
    crz = eB.x*vd1 - eB.y*vd0;
    av0 += sed*eB.x + gates*vb0 + cpg*crx;
    av1 += sed*eB.y + gates*vb1 + cpg*cry;
    av2 += sed*eB.z + gates*vb2 + cpg*crz;
  }
  if (p < pend) {
    int  sA_ = srcp[p];
    float4 eA = edata[p];
    float4 Aa = Aout4[(long)sA_*32 + g];
    const float* vpa = v_prev + (long)sA_*96 + g*3;
    float va0 = vpa[0], va1 = vpa[1], va2 = vpa[2];
    float xa = eA.w * inv_step;
    float fa = floorf(xa);
    int ia = (int)fa; if (ia > TBL-1) ia = TBL-1;
    float fra = xa - fa;
    float4 m0a = tbl4[(long)ia*32 + g],  m1a = tbl4[(long)(ia+1)*32 + g];
    float ga = m0a.x + fra*(m1a.x - m0a.x);
    float ca = m0a.y + fra*(m1a.y - m0a.y);
    float da = m0a.z + fra*(m1a.z - m0a.z);
    float sa = m0a.w + fra*(m1a.w - m0a.w);
    float gates = ga*Aa.x, cpg = ca*Aa.y, sed = da*Aa.z;
    acc_s += sa*Aa.w;
    float crx = eA.y*vd2 - eA.z*vd1;
    float cry = eA.z*vd0 - eA.x*vd2;
    float crz = eA.x*vd1 - eA.y*vd0;
    av0 += sed*eA.x + gates*va0 + cpg*crx;
    av1 += sed*eA.y + gates*va1 + cpg*cry;
    av2 += sed*eA.z + gates*va2 + cpg*crz;
  }
  // combine the two halves
  av0   += __shfl_xor(av0, 32);
  av1   += __shfl_xor(av1, 32);
  av2   += __shfl_xor(av2, 32);
  acc_s += __shfl_xor(acc_s, 32);

  // ---- fused node update (weights straight from global: L1/L2-hot) ----
  float nv0 = vd0 + av0, nv1 = vd1 + av1, nv2 = vd2 + av2;
  float ns  = s_own + acc_s;
  if (hf == 0) {
    vld[w][g*3+0] = nv0; vld[w][g*3+1] = nv1; vld[w][g*3+2] = nv2;
  }
  __syncthreads();
  float Vv0=0,Vv1=0,Vv2=0,Uv0=0,Uv1=0,Uv2=0;
  for (int f = 0; f < 32; ++f) {
    float wu = uU[f*32 + g];
    float wv = uV[f*32 + g];
    float v0 = vld[w][f*3+0], v1 = vld[w][f*3+1], v2 = vld[w][f*3+2];
    Vv0 += v0*wv; Vv1 += v1*wv; Vv2 += v2*wv;
    Uv0 += v0*wu; Uv1 += v1*wu; Uv2 += v2*wu;
  }
  float Vn = sqrtf(Vv0*Vv0 + Vv1*Vv1 + Vv2*Vv2);
  if (hf == 0) { in64[w][g] = Vn; in64[w][32 + g] = ns; }
  __syncthreads();
  float h = ub1[g];
  for (int k = 0; k < 64; ++k) h += in64[w][k] * uw1[k*32 + g];
  h = fsilu(h);
  if (hf == 0) hld[w][g] = h;
  __syncthreads();
  float og = ub2[g], ossn = ub2[32 + g], oadd = ub2[64 + g];
  for (int k = 0; k < 32; ++k) {
    float hk = hld[w][k];
    og   += hk * uw2[k*96 +      g];
    ossn += hk * uw2[k*96 + 32 + g];
    oadd += hk * uw2[k*96 + 64 + g];
  }
  if (ok && hf == 0) {
    float* vo = v_out + (long)n*96 + g*3;
    vo[0] = nv0 + og*Uv0;
    vo[1] = nv1 + og*Uv1;
    vo[2] = nv2 + og*Uv2;
    s_out[(long)n*32 + g] = ns + Vn*Vn*ossn + oadd;
  }
}

// ---------------------------------------------------------------------------
// readout: inv|gates = mlp(s); eqv = gates * (v @ ro_V)
// ---------------------------------------------------------------------------
__global__ __launch_bounds__(256) void readout_kernel(
    const float* __restrict__ s_cur, const float* __restrict__ v_cur,
    const float* __restrict__ w1, const float* __restrict__ b1,
    const float* __restrict__ w2, const float* __restrict__ b2,
    const float* __restrict__ roV, float* __restrict__ out, int N_)
{
  __shared__ float sld[8][32];
  __shared__ float hld[8][32];
  __shared__ float vld[8][96];
  int tid = threadIdx.x, i = tid >> 5, g = tid & 31;
  long n = (long)blockIdx.x * 8 + i;
  bool ok = (n < N_);
  if (ok) {
    sld[i][g] = s_cur[n*32 + g];
    const float* vp = v_cur + n*96 + g*3;
    vld[i][g*3+0] = vp[0]; vld[i][g*3+1] = vp[1]; vld[i][g*3+2] = vp[2];
  } else {
    sld[i][g] = 0.f;
    vld[i][g*3+0] = vld[i][g*3+1] = vld[i][g*3+2] = 0.f;
  }
  __syncthreads();
  float h = b1[g];
  for (int k = 0; k < 32; ++k) h += sld[i][k] * w1[k*32 + g];
  h = fsilu(h);
  hld[i][g] = h;
  __syncthreads();
  float inv = b2[g], gate = b2[32+g];
  for (int k = 0; k < 32; ++k) {
    float hk = hld[i][k];
    inv  += hk * w2[k*64 +      g];
    gate += hk * w2[k*64 + 32 + g];
  }
  float R0=0, R1=0, R2=0;
  for (int f = 0; f < 32; ++f) {
    float wv = roV[f*32 + g];
    R0 += vld[i][f*3+0]*wv; R1 += vld[i][f*3+1]*wv; R2 += vld[i][f*3+2]*wv;
  }
  if (ok) {
    out[n*32 + g] = inv;
    long eb = (long)N_*32 + n*96 + (long)g*3;
    out[eb+0] = gate*R0; out[eb+1] = gate*R1; out[eb+2] = gate*R2;
  }
}

// ---------------------------------------------------------------------------
extern "C" void kernel_launch(void* const* d_in, const int* in_sizes, int n_in,
                              void* d_out, int out_size, void* d_ws, size_t ws_size,
                              hipStream_t stream)
{
  const float* s_in  = (const float*)d_in[0];
  const float* v_in  = (const float*)d_in[1];   // (N, F, 3)
  const int*   ei    = (const int*)  d_in[2];
  const float* dist  = (const float*)d_in[3];
  const float* edir  = (const float*)d_in[4];
  const float* mp_w1 = (const float*)d_in[5];
  const float* mp_b1 = (const float*)d_in[6];
  const float* mp_w2 = (const float*)d_in[7];
  const float* mp_b2 = (const float*)d_in[8];
  const float* mw_w1 = (const float*)d_in[9];
  const float* mw_b1 = (const float*)d_in[10];
  const float* mw_w2 = (const float*)d_in[11];
  const float* mw_b2 = (const float*)d_in[12];
  const float* u_U   = (const float*)d_in[13];
  const float* u_V   = (const float*)d_in[14];
  const float* u_w1  = (const float*)d_in[15];
  const float* u_b1  = (const float*)d_in[16];
  const float* u_w2  = (const float*)d_in[17];
  const float* u_b2  = (const float*)d_in[18];
  const float* ro_w1 = (const float*)d_in[19];
  const float* ro_b1 = (const float*)d_in[20];
  const float* ro_w2 = (const float*)d_in[21];
  const float* ro_b2 = (const float*)d_in[22];
  const float* ro_V  = (const float*)d_in[23];

  int N_ = in_sizes[0] / 32;
  int E_ = in_sizes[3];

  float*  sA    = (float*)d_ws;                       // N*32
  float*  vA    = sA + (size_t)N_*32;                 // N*96
  float*  sB    = vA + (size_t)N_*96;                 // N*32
  float*  vB    = sB + (size_t)N_*32;                 // N*96
  float4* Aout4 = (float4*)(vB + (size_t)N_*96);      // N*32 float4
  float4* tbl4  = Aout4 + (size_t)N_*32;              // (TBL+1)*32 float4
  float4* edata = tbl4 + (size_t)(TBL+1)*32;          // E float4
  int*    srcp  = (int*)(edata + (size_t)E_);         // E
  int*    deg   = srcp + E_;                          // N
  int*    off   = deg + N_;                           // N+1
  int*    cursor= off + N_ + 1;                       // N

  int nodeBlocks  = (N_ + 7) / 8;
  int gathBlocks  = (N_ + 3) / 4;
  int edgeBlocks  = (E_ + 255) / 256;
  int tblBlocks   = (TBL + 1 + 7) / 8;

  // --- CSR build (once; edge_index constant across layers) ---
  hipMemsetAsync(deg, 0, (size_t)N_ * sizeof(int), stream);
  hist_kernel<<<edgeBlocks, 256, 0, stream>>>(ei, deg, E_);
  scan_kernel<<<1, 1024, 0, stream>>>(deg, off, cursor, N_);
  scatter_kernel<<<edgeBlocks, 256, 0, stream>>>(ei, dist, edir, cursor, srcp, edata, E_);

  const float* s_cur = s_in;  const float* v_cur = v_in;
  float* s_nxt = sB;  float* v_nxt = vB;
  for (int l = 0; l < 2; ++l) {
    nodeA_kernel<<<nodeBlocks, 256, 0, stream>>>(
        s_cur, mp_w1 + l*1024, mp_b1 + l*32, mp_w2 + l*4096, mp_b2 + l*128, Aout4, N_);
    tbl_kernel<<<tblBlocks, 256, 0, stream>>>(
        mw_w1 + l*1024, mw_b1 + l*32, mw_w2 + l*4096, mw_b2 + l*128, tbl4);
    gather_update_kernel<<<gathBlocks, 256, 0, stream>>>(
        off, srcp, edata, tbl4, s_cur, v_cur, Aout4,
        u_U + l*1024, u_V + l*1024, u_w1 + l*2048, u_b1 + l*32,
        u_w2 + l*3072, u_b2 + l*96,
        s_nxt, v_nxt, N_);
    s_cur = s_nxt; v_cur = v_nxt;
    s_nxt = sA;    v_nxt = vA;     // layer1 writes the A buffers
  }

  readout_kernel<<<nodeBlocks, 256, 0, stream>>>(
      s_cur, v_cur, ro_w1, ro_b1, ro_w2, ro_b2, ro_V, (float*)d_out, N_);
}

// Round 4
// 688.936 us; speedup vs baseline: 15.7258x; 1.1364x over previous
//
#include <hip/hip_runtime.h>
#include <math.h>

#define PI_LEN 0.3141592653589793f   // pi / 10.0
#define LEN_F  10.0f
#define TBL    4096                   // table rows = TBL+1

__device__ __forceinline__ float fsilu(float x) {
  return x * __builtin_amdgcn_rcpf(1.f + __expf(-x));
}

// ---------------------------------------------------------------------------
// CSR build: hist -> scan -> scatter (edge_index constant across layers)
// ---------------------------------------------------------------------------
__global__ __launch_bounds__(256) void hist_kernel(const int* __restrict__ ei,
                                                   int* __restrict__ deg, int E_) {
  int e = blockIdx.x * 256 + threadIdx.x;
  if (e < E_) atomicAdd(&deg[ei[E_ + e]], 1);
}

__global__ __launch_bounds__(1024) void scan_kernel(const int* __restrict__ deg,
                                                    int* __restrict__ off,
                                                    int* __restrict__ cursor, int N_) {
  __shared__ int wtot[16];
  __shared__ int carry_s;
  int tid = threadIdx.x, lane = tid & 63, wid = tid >> 6;
  if (tid == 0) carry_s = 0;
  __syncthreads();
  int nch = (N_ + 8191) / 8192;
  for (int c = 0; c < nch; ++c) {
    int base_idx = c * 8192 + tid * 8;
    int x[8]; int mysum = 0;
    #pragma unroll
    for (int j = 0; j < 8; ++j) { int idx = base_idx + j; x[j] = (idx < N_) ? deg[idx] : 0; mysum += x[j]; }
    int incl = mysum;
    #pragma unroll
    for (int s = 1; s < 64; s <<= 1) { int t = __shfl_up(incl, s, 64); if (lane >= s) incl += t; }
    if (lane == 63) wtot[wid] = incl;
    __syncthreads();
    if (wid == 0) {
      int wt = (lane < 16) ? wtot[lane] : 0;
      #pragma unroll
      for (int s = 1; s < 16; s <<= 1) { int t = __shfl_up(wt, s, 64); if (lane >= s) wt += t; }
      if (lane < 16) wtot[lane] = wt;
    }
    __syncthreads();
    int wexcl = (wid > 0) ? wtot[wid - 1] : 0;
    int run = carry_s + wexcl + (incl - mysum);
    #pragma unroll
    for (int j = 0; j < 8; ++j) {
      int idx = base_idx + j;
      if (idx < N_) { off[idx] = run; cursor[idx] = run; }
      run += x[j];
    }
    __syncthreads();
    if (tid == 0) carry_s += wtot[15];
    __syncthreads();
  }
  if (tid == 0) off[N_] = carry_s;
}

__global__ __launch_bounds__(256) void scatter_kernel(
    const int* __restrict__ ei, const float* __restrict__ dist,
    const float* __restrict__ edir, int* __restrict__ cursor,
    int* __restrict__ srcp, float4* __restrict__ edata, int E_) {
  int e = blockIdx.x * 256 + threadIdx.x;
  if (e < E_) {
    int dst = ei[E_ + e];
    int pos = atomicAdd(&cursor[dst], 1);
    srcp[pos] = ei[e];
    edata[pos] = make_float4(edir[3*e], edir[3*e+1], edir[3*e+2], dist[e]);
  }
}

// ---------------------------------------------------------------------------
// nodeA: A[n] = silu(s[n] @ w1 + b1) @ w2 + b2 ; Aout4[n*32+g] =
//   (gates_col, cpg_col, sed_col, sf_col * s[n][g])   <- s folded into .w
// ---------------------------------------------------------------------------
__global__ __launch_bounds__(256) void nodeA_kernel(
    const float* __restrict__ s, const float* __restrict__ w1,
    const float* __restrict__ b1, const float* __restrict__ w2,
    const float* __restrict__ b2, float4* __restrict__ Aout4, int N_)
{
  __shared__ float xld[8][32];
  __shared__ float hld[8][32];
  int tid = threadIdx.x, i = tid >> 5, g = tid & 31;
  long n = (long)blockIdx.x * 8 + i;
  bool ok = (n < N_);
  xld[i][g] = ok ? s[n*32 + g] : 0.f;
  __syncthreads();
  float acc = b1[g];
  for (int k = 0; k < 32; ++k) acc += xld[i][k] * w1[k*32 + g];
  hld[i][g] = fsilu(acc);
  __syncthreads();
  float o0 = b2[g], o1 = b2[32+g], o2 = b2[64+g], o3 = b2[96+g];
  for (int k = 0; k < 32; ++k) {
    float hk = hld[i][k];
    o0 += hk * w2[k*128 +      g];
    o1 += hk * w2[k*128 + 32 + g];
    o2 += hk * w2[k*128 + 64 + g];
    o3 += hk * w2[k*128 + 96 + g];
  }
  if (ok) Aout4[n*32 + g] = make_float4(o0, o1, o2, o3 * xld[i][g]);
}

// ---------------------------------------------------------------------------
// filter table: tbl4[t*32+g] = mlpB(posenc(t*LEN/TBL)) packed (q0..q3) at g
// ---------------------------------------------------------------------------
__global__ __launch_bounds__(256) void tbl_kernel(
    const float* __restrict__ w1, const float* __restrict__ b1,
    const float* __restrict__ w2, const float* __restrict__ b2,
    float4* __restrict__ tbl4)
{
  __shared__ float peld[8][32];
  __shared__ float hld[8][32];
  int tid = threadIdx.x, i = tid >> 5, g = tid & 31;
  int t = blockIdx.x * 8 + i;
  bool okt = (t <= TBL);
  float d = (float)t * (LEN_F / (float)TBL);
  float pe = (g < 16) ? __sinf(d * (float)(g + 1) * PI_LEN)
                      : __cosf(d * (float)(g - 15) * PI_LEN);
  peld[i][g] = pe;
  __syncthreads();
  float h = b1[g];
  for (int k = 0; k < 32; ++k) h += peld[i][k] * w1[k*32 + g];
  hld[i][g] = fsilu(h);
  __syncthreads();
  float o0 = b2[g], o1 = b2[32+g], o2 = b2[64+g], o3 = b2[96+g];
  for (int k = 0; k < 32; ++k) {
    float hk = hld[i][k];
    o0 += hk * w2[k*128 +      g];
    o1 += hk * w2[k*128 + 32 + g];
    o2 += hk * w2[k*128 + 64 + g];
    o3 += hk * w2[k*128 + 96 + g];
  }
  if (okt) tbl4[(long)t*32 + g] = make_float4(o0, o1, o2, o3);
}

// ---------------------------------------------------------------------------
// gather: barrier-free, 4 nodes/block, one wave64/node, lane=(hf,g).
// Each half-wave takes alternating groups of 4 CSR slots -> 8 edges in
// flight per wave; ~16 outstanding loads per half before first use.
// Writes acc4[n*32+g] = (av0, av1, av2, acc_s).
// ---------------------------------------------------------------------------
#define EDGE_MATH(ED, M0, M1, FR, Av, V0, V1, V2)                         \
  {                                                                        \
    float ga = M0.x + FR*(M1.x - M0.x);                                    \
    float ca = M0.y + FR*(M1.y - M0.y);                                    \
    float da = M0.z + FR*(M1.z - M0.z);                                    \
    float sa = M0.w + FR*(M1.w - M0.w);                                    \
    float gates = ga*Av.x, cpg = ca*Av.y, sed = da*Av.z;                   \
    acc_s += sa*Av.w;                                                      \
    float crx = ED.y*vd2 - ED.z*vd1;                                       \
    float cry = ED.z*vd0 - ED.x*vd2;                                       \
    float crz = ED.x*vd1 - ED.y*vd0;                                       \
    av0 += sed*ED.x + gates*V0 + cpg*crx;                                  \
    av1 += sed*ED.y + gates*V1 + cpg*cry;                                  \
    av2 += sed*ED.z + gates*V2 + cpg*crz;                                  \
  }

__global__ __launch_bounds__(256) void gather_kernel(
    const int* __restrict__ off, const int* __restrict__ srcp,
    const float4* __restrict__ edata, const float4* __restrict__ tbl4,
    const float* __restrict__ v_prev, const float4* __restrict__ Aout4,
    float4* __restrict__ acc4, int N_)
{
  int tid = threadIdx.x, w = tid >> 6, lane = tid & 63, g = lane & 31, hf = lane >> 5;
  int n = blockIdx.x * 4 + w;
  if (n >= N_) return;                      // no barriers: early exit is safe
  const float* vp = v_prev + (long)n*96 + g*3;
  float vd0 = vp[0], vd1 = vp[1], vd2 = vp[2];
  int pstart = off[n], pend = off[n + 1];
  float acc_s = 0, av0 = 0, av1 = 0, av2 = 0;
  const float inv_step = (float)TBL / LEN_F;

  int deg = pend - pstart;
  int nfull = deg >> 3;                     // groups of 8 (4 per half)
  int pb = pstart + hf * 4;
  for (int it = 0; it < nfull; ++it, pb += 8) {
    int srcs[4]; float4 ed[4];
    #pragma unroll
    for (int b = 0; b < 4; ++b) { srcs[b] = srcp[pb + b]; ed[b] = edata[pb + b]; }
    float4 m0[4], m1[4], A[4]; float fr[4];
    float vs0[4], vs1[4], vs2[4];
    #pragma unroll
    for (int b = 0; b < 4; ++b) {
      float x = ed[b].w * inv_step;
      float f = floorf(x);
      int i0 = (int)f; if (i0 > TBL - 1) i0 = TBL - 1;
      fr[b] = x - f;
      m0[b] = tbl4[(long)i0*32 + g];
      m1[b] = tbl4[(long)(i0 + 1)*32 + g];
      A[b]  = Aout4[(long)srcs[b]*32 + g];
      const float* vq = v_prev + (long)srcs[b]*96 + g*3;
      vs0[b] = vq[0]; vs1[b] = vq[1]; vs2[b] = vq[2];
    }
    #pragma unroll
    for (int b = 0; b < 4; ++b)
      EDGE_MATH(ed[b], m0[b], m1[b], fr[b], A[b], vs0[b], vs1[b], vs2[b]);
  }
  // tail: up to 7 edges, 2 per half then 1
  int p = pstart + nfull * 8 + hf;
  for (; p + 2 < pend; p += 4) {
    int  s0_ = srcp[p], s1_ = srcp[p + 2];
    float4 e0 = edata[p], e1 = edata[p + 2];
    float x0 = e0.w * inv_step, x1 = e1.w * inv_step;
    float f0 = floorf(x0), f1 = floorf(x1);
    int i0 = (int)f0; if (i0 > TBL - 1) i0 = TBL - 1;
    int i1 = (int)f1; if (i1 > TBL - 1) i1 = TBL - 1;
    float r0 = x0 - f0, r1 = x1 - f1;
    float4 a0 = tbl4[(long)i0*32 + g], b0 = tbl4[(long)(i0+1)*32 + g];
    float4 a1 = tbl4[(long)i1*32 + g], b1 = tbl4[(long)(i1+1)*32 + g];
    float4 A0 = Aout4[(long)s0_*32 + g], A1 = Aout4[(long)s1_*32 + g];
    const float* vq0 = v_prev + (long)s0_*96 + g*3;
    const float* vq1 = v_prev + (long)s1_*96 + g*3;
    float u0 = vq0[0], u1 = vq0[1], u2 = vq0[2];
    float t0 = vq1[0], t1 = vq1[1], t2 = vq1[2];
    EDGE_MATH(e0, a0, b0, r0, A0, u0, u1, u2);
    EDGE_MATH(e1, a1, b1, r1, A1, t0, t1, t2);
  }
  if (p < pend) {
    int  s0_ = srcp[p];
    float4 e0 = edata[p];
    float x0 = e0.w * inv_step;
    float f0 = floorf(x0);
    int i0 = (int)f0; if (i0 > TBL - 1) i0 = TBL - 1;
    float r0 = x0 - f0;
    float4 a0 = tbl4[(long)i0*32 + g], b0 = tbl4[(long)(i0+1)*32 + g];
    float4 A0 = Aout4[(long)s0_*32 + g];
    const float* vq0 = v_prev + (long)s0_*96 + g*3;
    float u0 = vq0[0], u1 = vq0[1], u2 = vq0[2];
    EDGE_MATH(e0, a0, b0, r0, A0, u0, u1, u2);
  }
  av0   += __shfl_xor(av0, 32);
  av1   += __shfl_xor(av1, 32);
  av2   += __shfl_xor(av2, 32);
  acc_s += __shfl_xor(acc_s, 32);
  if (hf == 0) acc4[(long)n*32 + g] = make_float4(av0, av1, av2, acc_s);
}

// ---------------------------------------------------------------------------
// node update: 8 nodes/block, 32 lanes/node. Reads acc4, writes s_out/v_out.
// ---------------------------------------------------------------------------
__global__ __launch_bounds__(256) void update_kernel(
    const float* __restrict__ s_prev, const float* __restrict__ v_prev,
    const float4* __restrict__ acc4,
    const float* __restrict__ uU, const float* __restrict__ uV,
    const float* __restrict__ uw1, const float* __restrict__ ub1,
    const float* __restrict__ uw2, const float* __restrict__ ub2,
    float* __restrict__ s_out, float* __restrict__ v_out, int N_)
{
  __shared__ float vld[8][96];
  __shared__ float in64[8][64];
  __shared__ float hld[8][32];
  int tid = threadIdx.x, i = tid >> 5, g = tid & 31;
  long n = (long)blockIdx.x * 8 + i;
  bool ok = (n < N_);
  float nv0 = 0, nv1 = 0, nv2 = 0, ns = 0;
  if (ok) {
    float4 a = acc4[n*32 + g];
    const float* vp = v_prev + n*96 + g*3;
    nv0 = vp[0] + a.x; nv1 = vp[1] + a.y; nv2 = vp[2] + a.z;
    ns  = s_prev[n*32 + g] + a.w;
  }
  vld[i][g*3+0] = nv0; vld[i][g*3+1] = nv1; vld[i][g*3+2] = nv2;
  __syncthreads();
  float Vv0=0,Vv1=0,Vv2=0,Uv0=0,Uv1=0,Uv2=0;
  for (int f = 0; f < 32; ++f) {
    float wu = uU[f*32 + g];
    float wv = uV[f*32 + g];
    float v0 = vld[i][f*3+0], v1 = vld[i][f*3+1], v2 = vld[i][f*3+2];
    Vv0 += v0*wv; Vv1 += v1*wv; Vv2 += v2*wv;
    Uv0 += v0*wu; Uv1 += v1*wu; Uv2 += v2*wu;
  }
  float Vn = sqrtf(Vv0*Vv0 + Vv1*Vv1 + Vv2*Vv2);
  in64[i][g] = Vn; in64[i][32 + g] = ns;
  __syncthreads();
  float h = ub1[g];
  for (int k = 0; k < 64; ++k) h += in64[i][k] * uw1[k*32 + g];
  h = fsilu(h);
  hld[i][g] = h;
  __syncthreads();
  float og = ub2[g], ossn = ub2[32 + g], oadd = ub2[64 + g];
  for (int k = 0; k < 32; ++k) {
    float hk = hld[i][k];
    og   += hk * uw2[k*96 +      g];
    ossn += hk * uw2[k*96 + 32 + g];
    oadd += hk * uw2[k*96 + 64 + g];
  }
  if (ok) {
    float* vo = v_out + n*96 + g*3;
    vo[0] = nv0 + og*Uv0;
    vo[1] = nv1 + og*Uv1;
    vo[2] = nv2 + og*Uv2;
    s_out[n*32 + g] = ns + Vn*Vn*ossn + oadd;
  }
}

// ---------------------------------------------------------------------------
// readout: inv|gates = mlp(s); eqv = gates * (v @ ro_V)
// ---------------------------------------------------------------------------
__global__ __launch_bounds__(256) void readout_kernel(
    const float* __restrict__ s_cur, const float* __restrict__ v_cur,
    const float* __restrict__ w1, const float* __restrict__ b1,
    const float* __restrict__ w2, const float* __restrict__ b2,
    const float* __restrict__ roV, float* __restrict__ out, int N_)
{
  __shared__ float sld[8][32];
  __shared__ float hld[8][32];
  __shared__ float vld[8][96];
  int tid = threadIdx.x, i = tid >> 5, g = tid & 31;
  long n = (long)blockIdx.x * 8 + i;
  bool ok = (n < N_);
  if (ok) {
    sld[i][g] = s_cur[n*32 + g];
    const float* vp = v_cur + n*96 + g*3;
    vld[i][g*3+0] = vp[0]; vld[i][g*3+1] = vp[1]; vld[i][g*3+2] = vp[2];
  } else {
    sld[i][g] = 0.f;
    vld[i][g*3+0] = vld[i][g*3+1] = vld[i][g*3+2] = 0.f;
  }
  __syncthreads();
  float h = b1[g];
  for (int k = 0; k < 32; ++k) h += sld[i][k] * w1[k*32 + g];
  h = fsilu(h);
  hld[i][g] = h;
  __syncthreads();
  float inv = b2[g], gate = b2[32+g];
  for (int k = 0; k < 32; ++k) {
    float hk = hld[i][k];
    inv  += hk * w2[k*64 +      g];
    gate += hk * w2[k*64 + 32 + g];
  }
  float R0=0, R1=0, R2=0;
  for (int f = 0; f < 32; ++f) {
    float wv = roV[f*32 + g];
    R0 += vld[i][f*3+0]*wv; R1 += vld[i][f*3+1]*wv; R2 += vld[i][f*3+2]*wv;
  }
  if (ok) {
    out[n*32 + g] = inv;
    long eb = (long)N_*32 + n*96 + (long)g*3;
    out[eb+0] = gate*R0; out[eb+1] = gate*R1; out[eb+2] = gate*R2;
  }
}

// ---------------------------------------------------------------------------
extern "C" void kernel_launch(void* const* d_in, const int* in_sizes, int n_in,
                              void* d_out, int out_size, void* d_ws, size_t ws_size,
                              hipStream_t stream)
{
  const float* s_in  = (const float*)d_in[0];
  const float* v_in  = (const float*)d_in[1];   // (N, F, 3)
  const int*   ei    = (const int*)  d_in[2];
  const float* dist  = (const float*)d_in[3];
  const float* edir  = (const float*)d_in[4];
  const float* mp_w1 = (const float*)d_in[5];
  const float* mp_b1 = (const float*)d_in[6];
  const float* mp_w2 = (const float*)d_in[7];
  const float* mp_b2 = (const float*)d_in[8];
  const float* mw_w1 = (const float*)d_in[9];
  const float* mw_b1 = (const float*)d_in[10];
  const float* mw_w2 = (const float*)d_in[11];
  const float* mw_b2 = (const float*)d_in[12];
  const float* u_U   = (const float*)d_in[13];
  const float* u_V   = (const float*)d_in[14];
  const float* u_w1  = (const float*)d_in[15];
  const float* u_b1  = (const float*)d_in[16];
  const float* u_w2  = (const float*)d_in[17];
  const float* u_b2  = (const float*)d_in[18];
  const float* ro_w1 = (const float*)d_in[19];
  const float* ro_b1 = (const float*)d_in[20];
  const float* ro_w2 = (const float*)d_in[21];
  const float* ro_b2 = (const float*)d_in[22];
  const float* ro_V  = (const float*)d_in[23];

  int N_ = in_sizes[0] / 32;
  int E_ = in_sizes[3];

  float*  sA    = (float*)d_ws;                       // N*32
  float*  vA    = sA + (size_t)N_*32;                 // N*96
  float*  sB    = vA + (size_t)N_*96;                 // N*32
  float*  vB    = sB + (size_t)N_*32;                 // N*96
  float4* Aout4 = (float4*)(vB + (size_t)N_*96);      // N*32 float4
  float4* tbl4  = Aout4 + (size_t)N_*32;              // (TBL+1)*32 float4
  float4* edata = tbl4 + (size_t)(TBL+1)*32;          // E float4
  int*    srcp  = (int*)(edata + (size_t)E_);         // E
  int*    deg   = srcp + E_;                          // N
  int*    off   = deg + N_;                           // N+1
  int*    cursor= off + N_ + 1;                       // N

  // acc scratch: reuse d_out (N*128 floats == N*32 float4); readout
  // fully overwrites it at the end.
  float4* acc4  = (float4*)d_out;

  int nodeBlocks  = (N_ + 7) / 8;
  int gathBlocks  = (N_ + 3) / 4;
  int edgeBlocks  = (E_ + 255) / 256;
  int tblBlocks   = (TBL + 1 + 7) / 8;

  // --- CSR build (once; edge_index constant across layers) ---
  hipMemsetAsync(deg, 0, (size_t)N_ * sizeof(int), stream);
  hist_kernel<<<edgeBlocks, 256, 0, stream>>>(ei, deg, E_);
  scan_kernel<<<1, 1024, 0, stream>>>(deg, off, cursor, N_);
  scatter_kernel<<<edgeBlocks, 256, 0, stream>>>(ei, dist, edir, cursor, srcp, edata, E_);

  const float* s_cur = s_in;  const float* v_cur = v_in;
  float* s_nxt = sB;  float* v_nxt = vB;
  for (int l = 0; l < 2; ++l) {
    nodeA_kernel<<<nodeBlocks, 256, 0, stream>>>(
        s_cur, mp_w1 + l*1024, mp_b1 + l*32, mp_w2 + l*4096, mp_b2 + l*128, Aout4, N_);
    tbl_kernel<<<tblBlocks, 256, 0, stream>>>(
        mw_w1 + l*1024, mw_b1 + l*32, mw_w2 + l*4096, mw_b2 + l*128, tbl4);
    gather_kernel<<<gathBlocks, 256, 0, stream>>>(
        off, srcp, edata, tbl4, v_cur, Aout4, acc4, N_);
    update_kernel<<<nodeBlocks, 256, 0, stream>>>(
        s_cur, v_cur, acc4,
        u_U + l*1024, u_V + l*1024, u_w1 + l*2048, u_b1 + l*32,
        u_w2 + l*3072, u_b2 + l*96,
        s_nxt, v_nxt, N_);
    s_cur = s_nxt; v_cur = v_nxt;
    s_nxt = sA;    v_nxt = vA;     // layer1 writes the A buffers
  }

  readout_kernel<<<nodeBlocks, 256, 0, stream>>>(
      s_cur, v_cur, ro_w1, ro_b1, ro_w2, ro_b2, ro_V, (float*)d_out, N_);
}